// Round 1
// baseline (141.537 us; speedup 1.0000x reference)
//
#include <hip/hip_runtime.h>

// SyntheticTripletLoss: B=32, T=512, D=512 fp32.
// Analytic collapse: with pt=dot(p,t), pp=dot(p,p), tt=dot(t,t):
//   norm^2 = pp - 2*pt^2 + pt^2*tt          (exact expansion of ||p - pt*t||^2)
//   sim_pn = (pp - pt^2) / max(norm, EPS)
//   loss   = max(0.5 + sim_pn - pt, 0), masked mean over t < len[b]
// Single pass over preds+targets (67 MB) -> memory-bound.

#define MARGIN 0.5f
#define EPS_N 1e-12f

static constexpr int BB = 32;
static constexpr int TT_DIM = 512;
static constexpr int DD = 512;

// one wave (64 lanes) per row; 4 waves per block; grid = B*T/4 = 4096 blocks
__global__ __launch_bounds__(256) void triplet_rows(
    const float* __restrict__ preds,
    const float* __restrict__ targets,
    const int* __restrict__ lengths,
    float* __restrict__ ws_sum)
{
    const int wave = threadIdx.x >> 6;
    const int lane = threadIdx.x & 63;
    const int row  = blockIdx.x * 4 + wave;          // [0, B*T)
    const int b    = row >> 9;                       // row / T
    const int t    = row & (TT_DIM - 1);             // row % T

    const float4* p4 = reinterpret_cast<const float4*>(preds   + (size_t)row * DD);
    const float4* t4 = reinterpret_cast<const float4*>(targets + (size_t)row * DD);

    float pp = 0.f, pt = 0.f, tt = 0.f;
    // 512 floats = 128 float4 per row; lanes take float4 idx {lane, lane+64}
    #pragma unroll
    for (int i = 0; i < 2; ++i) {
        float4 p = p4[lane + 64 * i];
        float4 q = t4[lane + 64 * i];
        pp += p.x * p.x + p.y * p.y + p.z * p.z + p.w * p.w;
        pt += p.x * q.x + p.y * q.y + p.z * q.z + p.w * q.w;
        tt += q.x * q.x + q.y * q.y + q.z * q.z + q.w * q.w;
    }

    // wave-64 shuffle reduction
    #pragma unroll
    for (int off = 32; off > 0; off >>= 1) {
        pp += __shfl_down(pp, off, 64);
        pt += __shfl_down(pt, off, 64);
        tt += __shfl_down(tt, off, 64);
    }

    __shared__ float block_loss[4];
    if (lane == 0) {
        float loss = 0.f;
        if (t < lengths[b]) {
            float pt2  = pt * pt;
            float n2   = pp - 2.f * pt2 + pt2 * tt;
            float nrm  = sqrtf(fmaxf(n2, 0.f));
            float spn  = (pp - pt2) / fmaxf(nrm, EPS_N);
            loss = fmaxf(MARGIN + spn - pt, 0.f);
        }
        block_loss[wave] = loss;
    }
    __syncthreads();
    if (threadIdx.x == 0) {
        float s = block_loss[0] + block_loss[1] + block_loss[2] + block_loss[3];
        atomicAdd(ws_sum, s);   // device-scope by default on CDNA
    }
}

__global__ void triplet_finalize(const float* __restrict__ ws_sum,
                                 const int* __restrict__ lengths,
                                 float* __restrict__ out)
{
    if (threadIdx.x == 0) {
        int denom = 0;
        #pragma unroll
        for (int b = 0; b < BB; ++b) denom += lengths[b];
        out[0] = ws_sum[0] / (float)denom;
    }
}

extern "C" void kernel_launch(void* const* d_in, const int* in_sizes, int n_in,
                              void* d_out, int out_size, void* d_ws, size_t ws_size,
                              hipStream_t stream)
{
    const float* preds   = (const float*)d_in[0];
    const float* targets = (const float*)d_in[1];
    const int*   lengths = (const int*)d_in[2];
    float* out = (float*)d_out;
    float* acc = (float*)d_ws;

    // d_ws is poisoned to 0xAA before every launch — zero the accumulator
    hipMemsetAsync(acc, 0, sizeof(float), stream);

    const int rows = BB * TT_DIM;          // 16384
    triplet_rows<<<rows / 4, 256, 0, stream>>>(preds, targets, lengths, acc);
    triplet_finalize<<<1, 64, 0, stream>>>(acc, lengths, out);
}

// Round 2
// 94.833 us; speedup vs baseline: 1.4925x; 1.4925x over previous
//
#include <hip/hip_runtime.h>

// SyntheticTripletLoss: B=32, T=512, D=512 fp32.
// Analytic collapse: with pt=dot(p,t), pp=dot(p,p), tt=dot(t,t):
//   norm^2 = pp - 2*pt^2 + pt^2*tt
//   sim_pn = (pp - pt^2) / max(norm, EPS)
//   loss   = max(0.5 + sim_pn - pt, 0), masked mean over t < len[b]
//
// R1 lesson: 4096 same-address atomicAdds serialized (~35 cyc each ≈ 60 µs).
// Now: plain per-block partial stores + tiny second-stage reduce. No atomics,
// no memset (ws[0..1023] fully overwritten every launch).

#define MARGIN 0.5f
#define EPS_N 1e-12f

static constexpr int BB     = 32;
static constexpr int TT_DIM = 512;
static constexpr int DD     = 512;
static constexpr int GRID1  = 1024;   // blocks in stage 1
static constexpr int ROWS_PER_WAVE = 4;

// 1024 blocks x 4 waves; each wave handles 4 consecutive rows.
__global__ __launch_bounds__(256) void triplet_rows(
    const float* __restrict__ preds,
    const float* __restrict__ targets,
    const int* __restrict__ lengths,
    float* __restrict__ ws_partial)
{
    const int wave  = threadIdx.x >> 6;
    const int lane  = threadIdx.x & 63;
    const int wglob = blockIdx.x * 4 + wave;            // [0, 4096)
    const int row0  = wglob * ROWS_PER_WAVE;            // 4 rows per wave

    float wacc = 0.f;

    #pragma unroll
    for (int r = 0; r < ROWS_PER_WAVE; ++r) {
        const int row = row0 + r;
        const int b   = row >> 9;                       // row / T
        const int t   = row & (TT_DIM - 1);             // row % T

        const float4* p4 = reinterpret_cast<const float4*>(preds   + (size_t)row * DD);
        const float4* t4 = reinterpret_cast<const float4*>(targets + (size_t)row * DD);

        float pp = 0.f, pt = 0.f, tt = 0.f;
        #pragma unroll
        for (int i = 0; i < 2; ++i) {
            float4 p = p4[lane + 64 * i];
            float4 q = t4[lane + 64 * i];
            pp += p.x * p.x + p.y * p.y + p.z * p.z + p.w * p.w;
            pt += p.x * q.x + p.y * q.y + p.z * q.z + p.w * q.w;
            tt += q.x * q.x + q.y * q.y + q.z * q.z + q.w * q.w;
        }

        // butterfly: all 64 lanes end with the full row sums
        #pragma unroll
        for (int m = 32; m > 0; m >>= 1) {
            pp += __shfl_xor(pp, m, 64);
            pt += __shfl_xor(pt, m, 64);
            tt += __shfl_xor(tt, m, 64);
        }

        // uniform per-row epilogue (all lanes identical)
        float pt2 = pt * pt;
        float n2  = pp - 2.f * pt2 + pt2 * tt;
        float nrm = sqrtf(fmaxf(n2, 0.f));
        float spn = (pp - pt2) / fmaxf(nrm, EPS_N);
        float l   = fmaxf(MARGIN + spn - pt, 0.f);
        if (t < lengths[b]) wacc += l;
    }

    __shared__ float wsum[4];
    if (lane == 0) wsum[wave] = wacc;
    __syncthreads();
    if (threadIdx.x == 0)
        ws_partial[blockIdx.x] = wsum[0] + wsum[1] + wsum[2] + wsum[3];
}

// single block: reduce 1024 partials, divide by sum(lengths)
__global__ __launch_bounds__(256) void triplet_finalize(
    const float* __restrict__ ws_partial,
    const int* __restrict__ lengths,
    float* __restrict__ out)
{
    const int tid  = threadIdx.x;
    const int wave = tid >> 6;
    const int lane = tid & 63;

    float s = ws_partial[tid] + ws_partial[tid + 256] +
              ws_partial[tid + 512] + ws_partial[tid + 768];

    #pragma unroll
    for (int m = 32; m > 0; m >>= 1) s += __shfl_xor(s, m, 64);

    __shared__ float wsum[4];
    if (lane == 0) wsum[wave] = s;
    __syncthreads();
    if (tid == 0) {
        float total = wsum[0] + wsum[1] + wsum[2] + wsum[3];
        int denom = 0;
        #pragma unroll
        for (int b = 0; b < BB; ++b) denom += lengths[b];
        out[0] = total / (float)denom;
    }
}

extern "C" void kernel_launch(void* const* d_in, const int* in_sizes, int n_in,
                              void* d_out, int out_size, void* d_ws, size_t ws_size,
                              hipStream_t stream)
{
    const float* preds   = (const float*)d_in[0];
    const float* targets = (const float*)d_in[1];
    const int*   lengths = (const int*)d_in[2];
    float* out = (float*)d_out;
    float* part = (float*)d_ws;   // 1024 floats, fully overwritten each launch

    triplet_rows<<<GRID1, 256, 0, stream>>>(preds, targets, lengths, part);
    triplet_finalize<<<1, 256, 0, stream>>>(part, lengths, out);
}

// Round 3
// 93.129 us; speedup vs baseline: 1.5198x; 1.0183x over previous
//
#include <hip/hip_runtime.h>

// SyntheticTripletLoss: B=32, T=512, D=512 fp32.
// Analytic collapse: with pt=dot(p,t), pp=dot(p,p), tt=dot(t,t):
//   norm^2 = pp - 2*pt^2 + pt^2*tt
//   sim_pn = (pp - pt^2) / max(norm, EPS)
//   loss   = max(0.5 + sim_pn - pt, 0), masked mean over t < len[b]
//
// R1: same-address atomics serialized (60 us) -> per-block partials.
// R2: grid 1024 -> 16 waves/CU = 52% occupancy, latency-bound.
// R3: 2048 blocks x 4 waves, 2 rows/wave -> 32 waves/CU (100%), 8 independent
//     float4-pair loads per wave; single-wave finalize (float4 partial reads).

#define MARGIN 0.5f
#define EPS_N 1e-12f

static constexpr int BB     = 32;
static constexpr int TT_DIM = 512;
static constexpr int DD     = 512;
static constexpr int GRID1  = 2048;   // blocks in stage 1
static constexpr int ROWS_PER_WAVE = 2;

// 2048 blocks x 4 waves; each wave handles 2 consecutive rows.
__global__ __launch_bounds__(256) void triplet_rows(
    const float* __restrict__ preds,
    const float* __restrict__ targets,
    const int* __restrict__ lengths,
    float* __restrict__ ws_partial)
{
    const int wave  = threadIdx.x >> 6;
    const int lane  = threadIdx.x & 63;
    const int wglob = blockIdx.x * 4 + wave;            // [0, 8192)
    const int row0  = wglob * ROWS_PER_WAVE;

    float wacc = 0.f;

    #pragma unroll
    for (int r = 0; r < ROWS_PER_WAVE; ++r) {
        const int row = row0 + r;
        const int b   = row >> 9;                       // row / T
        const int t   = row & (TT_DIM - 1);             // row % T

        const float4* p4 = reinterpret_cast<const float4*>(preds   + (size_t)row * DD);
        const float4* t4 = reinterpret_cast<const float4*>(targets + (size_t)row * DD);

        // issue all 4 loads for this row up front (independent)
        float4 pa = p4[lane];
        float4 qa = t4[lane];
        float4 pb = p4[lane + 64];
        float4 qb = t4[lane + 64];

        float pp = pa.x * pa.x + pa.y * pa.y + pa.z * pa.z + pa.w * pa.w
                 + pb.x * pb.x + pb.y * pb.y + pb.z * pb.z + pb.w * pb.w;
        float pt = pa.x * qa.x + pa.y * qa.y + pa.z * qa.z + pa.w * qa.w
                 + pb.x * qb.x + pb.y * qb.y + pb.z * qb.z + pb.w * qb.w;
        float tt = qa.x * qa.x + qa.y * qa.y + qa.z * qa.z + qa.w * qa.w
                 + qb.x * qb.x + qb.y * qb.y + qb.z * qb.z + qb.w * qb.w;

        // butterfly: all 64 lanes end with the full row sums
        #pragma unroll
        for (int m = 32; m > 0; m >>= 1) {
            pp += __shfl_xor(pp, m, 64);
            pt += __shfl_xor(pt, m, 64);
            tt += __shfl_xor(tt, m, 64);
        }

        // uniform per-row epilogue (all lanes identical)
        float pt2 = pt * pt;
        float n2  = pp - 2.f * pt2 + pt2 * tt;
        float nrm = sqrtf(fmaxf(n2, 0.f));
        float spn = (pp - pt2) / fmaxf(nrm, EPS_N);
        float l   = fmaxf(MARGIN + spn - pt, 0.f);
        if (t < lengths[b]) wacc += l;
    }

    __shared__ float wsum[4];
    if (lane == 0) wsum[wave] = wacc;
    __syncthreads();
    if (threadIdx.x == 0)
        ws_partial[blockIdx.x] = wsum[0] + wsum[1] + wsum[2] + wsum[3];
}

// single wave: reduce 2048 partials (8 float4 per lane), divide by sum(lengths)
__global__ __launch_bounds__(64) void triplet_finalize(
    const float* __restrict__ ws_partial,
    const int* __restrict__ lengths,
    float* __restrict__ out)
{
    const int lane = threadIdx.x & 63;
    const float4* p4 = reinterpret_cast<const float4*>(ws_partial);

    float s = 0.f;
    #pragma unroll
    for (int i = 0; i < 8; ++i) {
        float4 v = p4[lane + 64 * i];   // 64 lanes * 8 * 4 = 2048 floats
        s += v.x + v.y + v.z + v.w;
    }

    #pragma unroll
    for (int m = 32; m > 0; m >>= 1) s += __shfl_xor(s, m, 64);

    if (lane == 0) {
        int denom = 0;
        #pragma unroll
        for (int b = 0; b < BB; ++b) denom += lengths[b];
        out[0] = s / (float)denom;
    }
}

extern "C" void kernel_launch(void* const* d_in, const int* in_sizes, int n_in,
                              void* d_out, int out_size, void* d_ws, size_t ws_size,
                              hipStream_t stream)
{
    const float* preds   = (const float*)d_in[0];
    const float* targets = (const float*)d_in[1];
    const int*   lengths = (const int*)d_in[2];
    float* out  = (float*)d_out;
    float* part = (float*)d_ws;   // GRID1 floats, fully overwritten each launch

    triplet_rows<<<GRID1, 256, 0, stream>>>(preds, targets, lengths, part);
    triplet_finalize<<<1, 64, 0, stream>>>(part, lengths, out);
}